// Round 8
// baseline (7369.960 us; speedup 1.0000x reference)
//
#include <hip/hip_runtime.h>
#include <cmath>

#define Mdim 32
#define Ndim 32
#define Tsteps 512
#define H1dim 5120
#define H2dim 4096
#define HIDdim 1000
#define NWG 256
#define NTHR 1024
#define POLLER 320   // wave 5 lane 0: dedicated S3 barrier poller

typedef unsigned int u32;
typedef unsigned short u16;
typedef unsigned int u32x4 __attribute__((ext_vector_type(4)));  // true 4-VGPR tuple

// bf16 copies (filled by convert kernels each call)
__device__ u16 g_w2b[H2dim * HIDdim];        // [4096][1000]
__device__ u16 g_w3t[H2dim * Mdim * Ndim];   // transposed: [4096][1024]

// ---- LDS layout (bytes) ----
#define OFF_WIH 0          // 12 x 5120 bf16 = 122880
#define OFF_WHH 122880     // 12 x 1000 bf16 = 24000
#define OFF_UNION 146880   // 10240: s_x bf16[5120] | s_pd f32[512]
#define OFF_H9 157120      // padded h: 125 chunks x 9 f32 = 4520
#define OFF_MISC 161640    // 216 floats
#define SMEM_BYTES 162560

#define MI_POST 0
#define MI_PRIOR 32
#define MI_INNOV 96
#define MI_KIN 128
#define MI_GI 192
#define MI_GH 204

__device__ __forceinline__ u16 f2bf(float f) {
  u32 u = __float_as_uint(f);
  return (u16)((u + 0x7fffu + ((u >> 16) & 1u)) >> 16);
}
__device__ __forceinline__ float bflo(u32 u) { return __uint_as_float(u << 16); }
__device__ __forceinline__ float bfhi(u32 u) { return __uint_as_float(u & 0xffff0000u); }

__device__ __forceinline__ float dot4(float4 a, float4 b) {
  return a.x * b.x + a.y * b.y + a.z * b.z + a.w * b.w;
}
__device__ __forceinline__ float dot8_bb(uint4 a, uint4 b) {
  float s = 0.f;
  s = fmaf(bflo(a.x), bflo(b.x), s); s = fmaf(bfhi(a.x), bfhi(b.x), s);
  s = fmaf(bflo(a.y), bflo(b.y), s); s = fmaf(bfhi(a.y), bfhi(b.y), s);
  s = fmaf(bflo(a.z), bflo(b.z), s); s = fmaf(bfhi(a.z), bfhi(b.z), s);
  s = fmaf(bflo(a.w), bflo(b.w), s); s = fmaf(bfhi(a.w), bfhi(b.w), s);
  return s;
}
__device__ __forceinline__ float dot8_bf(uint4 a, const float* x8) {
  float s = 0.f;
  s = fmaf(bflo(a.x), x8[0], s); s = fmaf(bfhi(a.x), x8[1], s);
  s = fmaf(bflo(a.y), x8[2], s); s = fmaf(bfhi(a.y), x8[3], s);
  s = fmaf(bflo(a.z), x8[4], s); s = fmaf(bfhi(a.z), x8[5], s);
  s = fmaf(bflo(a.w), x8[6], s); s = fmaf(bfhi(a.w), x8[7], s);
  return s;
}

__device__ __forceinline__ float wave_reduce64(float v) {
#pragma unroll
  for (int off = 32; off >= 1; off >>= 1) v += __shfl_xor(v, off, 64);
  return v;
}

// ---- uncached (coherence-point) access helpers ----
__device__ __forceinline__ uint4 ldg_cg4u(const void* p) {
  uint4 r;
  asm volatile("global_load_dwordx4 %0, %1, off sc0 sc1\n\ts_waitcnt vmcnt(0)"
               : "=v"(r) : "v"(p) : "memory");
  return r;
}
__device__ __forceinline__ float ldg_cg1f(const float* p) {
  float r;
  asm volatile("global_load_dword %0, %1, off sc0 sc1\n\ts_waitcnt vmcnt(0)"
               : "=v"(r) : "v"(p) : "memory");
  return r;
}
__device__ __forceinline__ void stg_cg4u(void* p, u32 a, u32 b, u32 c, u32 d) {
  u32x4 v; v.x = a; v.y = b; v.z = c; v.w = d;   // ext_vector: valid "v" input
  asm volatile("global_store_dwordx4 %0, %1, off sc0 sc1" :: "v"(p), "v"(v) : "memory");
}

// ---- two-level grid barrier (R5-proven): 16 group counters (<=16 writers each)
// -> level-2 counter -> go line (ONE write per barrier; pollers read only).
__device__ __forceinline__ void gb_arrive(u32* bar) {
  asm volatile("s_waitcnt vmcnt(0)" ::: "memory");
  __syncthreads();
  if (threadIdx.x == POLLER) {
    u32 g = (u32)blockIdx.x & 15u;
    u32 a = __hip_atomic_fetch_add(bar + g * 16, 1u, __ATOMIC_RELAXED,
                                   __HIP_MEMORY_SCOPE_AGENT);
    if ((a & 15u) == 15u) {
      u32 b = __hip_atomic_fetch_add(bar + 256, 1u, __ATOMIC_RELAXED,
                                     __HIP_MEMORY_SCOPE_AGENT);
      if ((b & 15u) == 15u)
        __hip_atomic_fetch_add(bar + 320, 1u, __ATOMIC_RELAXED,
                               __HIP_MEMORY_SCOPE_AGENT);
    }
  }
}
__device__ __forceinline__ void gb_wait(u32* bar, u32 nb) {
  if (threadIdx.x == POLLER) {
    while (__hip_atomic_load(bar + 320, __ATOMIC_RELAXED,
                             __HIP_MEMORY_SCOPE_AGENT) < nb)
      __builtin_amdgcn_s_sleep(1);
  }
  __syncthreads();
}

__global__ void convert_w2(const float* __restrict__ W2) {
  int i = blockIdx.x * 1024 + threadIdx.x;
  if (i < H2dim * HIDdim) g_w2b[i] = f2bf(W2[i]);
}

__global__ void convert_w3t(const float* __restrict__ W3) {
  __shared__ float tile[32][33];
  int tr = blockIdx.x >> 7;    // 0..31
  int tc = blockIdx.x & 127;   // 0..127
  int r0 = tr * 32, c0 = tc * 32;
  int j = threadIdx.x & 31, i0 = threadIdx.x >> 5;
#pragma unroll
  for (int p = 0; p < 4; ++p) {
    int i = i0 + p * 8;
    tile[i][j] = W3[(size_t)(r0 + i) * H2dim + c0 + j];
  }
  __syncthreads();
#pragma unroll
  for (int p = 0; p < 4; ++p) {
    int i = i0 + p * 8;
    g_w3t[(size_t)(c0 + i) * 1024 + r0 + j] = f2bf(tile[j][i]);
  }
}

// Delta reduction: 32 global f32 atomic accumulators, double-buffered by step
// parity. C_t atomics -> acc[t&1]; A_t reads acc[(t-1)&1]; wg0 zeroes the
// consumed buffer after its x-poll completes (x complete => every WG published
// x_t => every WG finished A_t reads). The zero is drained by gb_arrive's
// vmcnt before wg0's S3_t arrival, which orders it before any C_{t+2} atomic.
// x/h exchanges: tagged single-transaction stores (R7-proven).
__global__ void __launch_bounds__(NTHR)
knet_kernel(const float* __restrict__ y, const float* __restrict__ F,
            const float* __restrict__ Hm, const float* __restrict__ m1x0,
            const float* __restrict__ h0, const float* __restrict__ W1,
            const float* __restrict__ b1, const float* __restrict__ Wih,
            const float* __restrict__ bih, const float* __restrict__ Whh,
            const float* __restrict__ bhh, const float* __restrict__ b2,
            const float* __restrict__ b3, float* __restrict__ out,
            u32* bar, u32* xbt, u32* hbt, float* acc) {
  extern __shared__ char smem[];
  u16* s_wih = (u16*)(smem + OFF_WIH);
  u16* s_whh = (u16*)(smem + OFF_WHH);
  u16* s_x = (u16*)(smem + OFF_UNION);
  float* s_pd = (float*)(smem + OFF_UNION);
  float* s_h9 = (float*)(smem + OFF_H9);
  float* s_m = (float*)(smem + OFF_MISC);
  float* s_post = s_m + MI_POST;
  float* s_prior = s_m + MI_PRIOR;
  float* s_innov = s_m + MI_INNOV;
  float* s_kin = s_m + MI_KIN;
  float* s_gi = s_m + MI_GI;
  float* s_gh = s_m + MI_GH;

  const int tid = threadIdx.x;
  const int w = tid >> 6;
  const int lane = tid & 63;
  const int wg = blockIdx.x;
  const int k0 = wg * 4;
  const bool gru_wg = (wg < 250);
  u32 nb = 0;

  // ---------------- prologue: LDS weight staging ----------------
  if (gru_wg) {
#pragma unroll 1
    for (int r = 0; r < 12; ++r) {
      const float* src = Wih + (size_t)((r >> 2) * HIDdim + k0 + (r & 3)) * H1dim;
      u16* dst = s_wih + r * H1dim;
      for (int e = tid; e < H1dim; e += NTHR) dst[e] = f2bf(src[e]);
    }
#pragma unroll 1
    for (int r = 0; r < 12; ++r) {
      const float* src = Whh + (size_t)((r >> 2) * HIDdim + k0 + (r & 3)) * HIDdim;
      u16* dst = s_whh + r * HIDdim;
      for (int e = tid; e < HIDdim; e += NTHR) dst[e] = f2bf(src[e]);
    }
  }
  if (tid < 250) {
    float4 hv = ((const float4*)h0)[tid];
    int b0 = tid * 4;
    s_h9[((b0 + 0) >> 3) * 9 + ((b0 + 0) & 7)] = hv.x;
    s_h9[((b0 + 1) >> 3) * 9 + ((b0 + 1) & 7)] = hv.y;
    s_h9[((b0 + 2) >> 3) * 9 + ((b0 + 2) & 7)] = hv.z;
    s_h9[((b0 + 3) >> 3) * 9 + ((b0 + 3) & 7)] = hv.w;
  }
  __syncthreads();

  const int c2 = wg * 16 + w;            // this wave's W2/W3t row
  // wave-0 persistent state: prior (lanes<32), prefetched y row, b3·innov term
  float prior = 0.f, bb = 0.f, yv = 0.f;
  if (w == 0 && lane < 32) {
    prior = m1x0[lane];
    yv = y[lane];  // y row 0
  }

  // gh: Whh @ h (needs staged s_whh/s_h9)
  auto gh_compute = [&]() {
    int base = (w - 12) * 3;
#pragma unroll
    for (int rr = 0; rr < 3; ++rr) {
      int r = base + rr;
      const uint4* wr = (const uint4*)(s_whh + r * HIDdim);
      float acc_ = dot8_bf(wr[lane], s_h9 + lane * 9);
      if (lane < 61) acc_ += dot8_bf(wr[lane + 64], s_h9 + (lane + 64) * 9);
      acc_ = wave_reduce64(acc_);
      if (lane == 0) s_gh[r] = acc_ + bhh[(r >> 2) * HIDdim + k0 + (r & 3)];
    }
  };
  if (gru_wg && w >= 12) gh_compute();

  for (int t = 0; t < Tsteps; ++t) {
    const u32 want = (u32)(t + 1);
    const int parR = (t + 1) & 1;   // buffer consumed this step ((t-1)&1)
    const int parW = t & 1;         // buffer C_t accumulates into
    // ---------------- Phase A: serial chain (wave 0 only) ----------------
    if (w == 0) {
      float p = 0.f, inn = 0.f;
      float prev = prior;
      if (lane < 32) {
        if (t == 0) {
          p = m1x0[lane];
        } else {
          float d = ldg_cg1f(acc + parR * 32 + lane);  // atomic-summed delta
          p = prior + d + bb;  // bb = b3·innov from last S3 shadow
          if (wg == 0) out[(t - 1) * Mdim + lane] = p;
        }
        s_post[lane] = p;
      }
      asm volatile("" ::: "memory");
      if (lane < 32) {  // prior = F @ post
        const float4* Fr = (const float4*)(F + lane * Mdim);
        const float4* pp = (const float4*)s_post;
        float s = 0.f;
#pragma unroll
        for (int j = 0; j < 8; ++j) s += dot4(Fr[j], pp[j]);
        prior = s;
        s_prior[lane] = s;
      }
      asm volatile("" ::: "memory");
      if (lane < 32) {  // innov = y_t - H @ prior
        const float4* Hr = (const float4*)(Hm + lane * Mdim);
        const float4* pp = (const float4*)s_prior;
        float s = 0.f;
#pragma unroll
        for (int j = 0; j < 8; ++j) s += dot4(Hr[j], pp[j]);
        inn = yv - s;
        s_innov[lane] = inn;
      }
      // kin: lanes<32 innov, lanes>=32 (post - prev_prior); normalize halves
      float vd = __shfl(p, lane & 31, 64) - __shfl(prev, lane & 31, 64);
      float v = (lane < 32) ? inn : vd;
      float sq = v * v;
#pragma unroll
      for (int off = 16; off >= 1; off >>= 1) sq += __shfl_xor(sq, off, 32);
      s_kin[lane] = v / fmaxf(sqrtf(sq), 1e-12f);
    }
    __syncthreads();   // publish s_innov/s_kin

    // ---- wave 0: W1 rows (3 lanes/row) -> pack -> tagged x store ----
    if (w == 0) {
      int r = lane / 3;
      int p = lane - r * 3;
      float acc_ = 0.f;
      if (r < 20) {
        const float4* Wr = (const float4*)W1 + (size_t)(wg * 20 + r) * 16;
        const float4* kc = (const float4*)s_kin;
#pragma unroll
        for (int c = p; c < 16; c += 3) acc_ += dot4(Wr[c], kc[c]);
      }
      int rr = (r < 20) ? r : 0;
      float a1v = __shfl(acc_, rr * 3 + 1, 64);
      float a2v = __shfl(acc_, rr * 3 + 2, 64);
      u32 myval = 0;
      if (r < 20 && p == 0)
        myval = (u32)f2bf(fmaxf(acc_ + a1v + a2v + b1[wg * 20 + r], 0.f));
      u32 vs[7];
      int q = (lane < 3) ? lane : 0;
#pragma unroll
      for (int s2 = 0; s2 < 7; ++s2) {
        int ridx = q * 7 + s2;
        vs[s2] = __shfl(myval, (ridx < 20 ? ridx : 0) * 3, 64);
      }
      if (lane < 3) {
        stg_cg4u((char*)xbt + (size_t)(wg * 3 + lane) * 16,
                 vs[0] | (vs[1] << 16),
                 vs[2] | (vs[3] << 16),
                 vs[4] | (vs[5] << 16),
                 ((lane == 2) ? 0u : vs[6]) | (want << 16));
      }
    }
    // ---- all waves: u = W3t row · innov, W2 row prefetch (h-independent;
    //      iteration-local register lifetimes — NOT loop-carried) ----
    float u;
    uint4 w2a, w2b_;
    {
      const uint4* tr3 = (const uint4*)(g_w3t + (size_t)c2 * 1024);
      uint4 t0 = tr3[2 * lane], t1 = tr3[2 * lane + 1];
      const float* iv = s_innov + 16 * (lane & 1);
      u = dot8_bf(t0, iv) + dot8_bf(t1, iv + 8);
      u += __shfl_xor(u, 1, 64);
      const uint4* w2p = (const uint4*)(g_w2b + (size_t)c2 * HIDdim);
      w2a = w2p[lane];
      w2b_ = (lane < 61) ? w2p[lane + 64] : make_uint4(0u, 0u, 0u, 0u);
    }
    // ---- x poll+stage: gru WGs, waves 4-15 own one group each ----
    if (gru_wg && tid >= 256) {
      int g = tid - 256;
      int swg = g / 3;
      int q = g - swg * 3;
      const char* gp = (const char*)xbt + (size_t)g * 16;
      uint4 v;
      for (;;) {
        v = ldg_cg4u(gp);
        if ((v.w >> 16) == want) break;
        __builtin_amdgcn_s_sleep(1);
      }
      u16* sx = (u16*)s_x;
      int base = swg * 20 + q * 7;
      sx[base + 0] = (u16)(v.x & 0xffff);
      sx[base + 1] = (u16)(v.x >> 16);
      sx[base + 2] = (u16)(v.y & 0xffff);
      sx[base + 3] = (u16)(v.y >> 16);
      sx[base + 4] = (u16)(v.z & 0xffff);
      sx[base + 5] = (u16)(v.z >> 16);
      if (q != 2) sx[base + 6] = (u16)(v.w & 0xffff);
    }
    __syncthreads();   // s_x ready (=> all 256 WGs published x => all A_t done)

    // ---- wg0: re-zero the consumed delta buffer (safe point — see header) ----
    if (wg == 0 && tid == 1016) {
      float* z = acc + parR * 32;
      stg_cg4u(z, 0u, 0u, 0u, 0u);
      stg_cg4u(z + 4, 0u, 0u, 0u, 0u);
      stg_cg4u(z + 8, 0u, 0u, 0u, 0u);
      stg_cg4u(z + 12, 0u, 0u, 0u, 0u);
      stg_cg4u(z + 16, 0u, 0u, 0u, 0u);
      stg_cg4u(z + 20, 0u, 0u, 0u, 0u);
      stg_cg4u(z + 24, 0u, 0u, 0u, 0u);
      stg_cg4u(z + 28, 0u, 0u, 0u, 0u);
    }

    // ---------------- gi: waves 0-11 ----------------
    if (gru_wg && w < 12) {
      const uint4* wr = (const uint4*)(s_wih + w * H1dim);
      const uint4* xr = (const uint4*)s_x;
      float acc_ = 0.f;
#pragma unroll
      for (int i = 0; i < 10; ++i) {
        int j = lane + 64 * i;
        acc_ += dot8_bb(wr[j], xr[j]);
      }
      acc_ = wave_reduce64(acc_);
      if (lane == 0) s_gi[w] = acc_ + bih[(w >> 2) * HIDdim + k0 + (w & 3)];
    }
    __syncthreads();   // s_gi ready

    // ---- gates -> tagged h store (wave 0 lanes 0-3; reads OLD s_h9 first) ----
    if (gru_wg && w == 0 && lane < 4) {
      int k = k0 + lane;
      float hold = s_h9[(k >> 3) * 9 + (k & 7)];
      float ir = s_gi[lane], iz = s_gi[4 + lane], ic = s_gi[8 + lane];
      float r = 1.f / (1.f + expf(-(ir + s_gh[lane])));
      float z = 1.f / (1.f + expf(-(iz + s_gh[4 + lane])));
      float c_ = tanhf(ic + r * s_gh[8 + lane]);
      float hv = (1.f - z) * c_ + z * hold;
      stg_cg4u((char*)hbt + (size_t)k * 16, __float_as_uint(hv), want, 0u, 0u);
    }
    // ---- h poll+stage: all WGs, one group per thread ----
    if (tid < HIDdim) {
      const char* gp = (const char*)hbt + (size_t)tid * 16;
      uint4 v;
      for (;;) {
        v = ldg_cg4u(gp);
        if (v.y == want) break;
        __builtin_amdgcn_s_sleep(1);
      }
      s_h9[(tid >> 3) * 9 + (tid & 7)] = __uint_as_float(v.x);
    }
    __syncthreads();   // s_h9 = h_t

    // ---------------- Phase C: l2 rows + delta atomics ----------------
    {
      float acc_ = dot8_bf(w2a, s_h9 + lane * 9);
      if (lane < 61) acc_ += dot8_bf(w2b_, s_h9 + (lane + 64) * 9);
      acc_ = wave_reduce64(acc_);
      float l2c = fmaxf(acc_ + b2[c2], 0.f);
      if ((lane & 1) == 0) s_pd[w * 32 + (lane >> 1)] = l2c * u;
    }
    __syncthreads();
    if (tid < 32) {
      float pdv = 0.f;
#pragma unroll
      for (int ww = 0; ww < 16; ++ww) pdv += s_pd[ww * 32 + tid];
      __hip_atomic_fetch_add(acc + parW * 32 + tid, pdv, __ATOMIC_RELAXED,
                             __HIP_MEMORY_SCOPE_AGENT);
    }
    ++nb;
    gb_arrive(bar);              // S3: delta atomics drained (sole barrier)
    // S3 shadow: next step's gh (Whh@h_t), b3·innov_t, y[t+1] prefetch
    if (gru_wg && w >= 12) gh_compute();
    if (w == 0 && lane < 32) {
      int tn = (t + 1 < Tsteps) ? t + 1 : Tsteps - 1;
      yv = y[tn * Ndim + lane];
      float b = 0.f;
#pragma unroll 8
      for (int j = 0; j < 32; ++j) b = fmaf(b3[lane * 32 + j], s_innov[j], b);
      bb = b;
    }
    gb_wait(bar, nb);
  }

  // ---------------- epilogue: out row 511 ----------------
  if (wg == 0 && w == 0 && lane < 32) {
    float d = ldg_cg1f(acc + ((Tsteps - 1) & 1) * 32 + lane);
    out[(Tsteps - 1) * Mdim + lane] = prior + d + bb;  // bb from last S3 shadow
  }
}

extern "C" void kernel_launch(void* const* d_in, const int* in_sizes, int n_in,
                              void* d_out, int out_size, void* d_ws, size_t ws_size,
                              hipStream_t stream) {
  const float* y    = (const float*)d_in[0];
  const float* F    = (const float*)d_in[1];
  const float* Hm   = (const float*)d_in[2];
  const float* m1x0 = (const float*)d_in[3];
  const float* h0   = (const float*)d_in[4];
  const float* W1   = (const float*)d_in[5];
  const float* b1   = (const float*)d_in[6];
  const float* Wih  = (const float*)d_in[7];
  const float* bih  = (const float*)d_in[8];
  const float* Whh  = (const float*)d_in[9];
  const float* bhh  = (const float*)d_in[10];
  const float* W2   = (const float*)d_in[11];
  const float* b2   = (const float*)d_in[12];
  const float* W3   = (const float*)d_in[13];
  const float* b3   = (const float*)d_in[14];
  float* out = (float*)d_out;

  // ws layout: bar[0,4096); acc@4096 (2x128B parity buffers);
  // xbt@8192 768x16B; hbt@20480 1000x16B. memset zeroes all control state.
  u32* bar   = (u32*)d_ws;
  float* acc = (float*)((char*)d_ws + 4096);
  u32* xbt   = (u32*)((char*)d_ws + 8192);
  u32* hbt   = (u32*)((char*)d_ws + 20480);

  convert_w2<<<4000, 1024, 0, stream>>>(W2);
  convert_w3t<<<4096, 256, 0, stream>>>(W3);
  hipMemsetAsync(d_ws, 0, 36864, stream);
  hipFuncSetAttribute((const void*)knet_kernel,
                      hipFuncAttributeMaxDynamicSharedMemorySize, SMEM_BYTES);
  void* args[] = {&y, &F, &Hm, &m1x0, &h0, &W1, &b1, &Wih, &bih, &Whh, &bhh,
                  &b2, &b3, &out, &bar, &xbt, &hbt, &acc};
  hipLaunchCooperativeKernel((const void*)knet_kernel, dim3(NWG), dim3(NTHR),
                             args, SMEM_BYTES, stream);
}

// Round 9
// 6025.785 us; speedup vs baseline: 1.2231x; 1.2231x over previous
//
#include <hip/hip_runtime.h>
#include <cmath>

#define Mdim 32
#define Ndim 32
#define Tsteps 512
#define H1dim 5120
#define H2dim 4096
#define HIDdim 1000
#define NWG 256
#define NTHR 1024
#define POLLER 320   // wave 5 lane 0: dedicated S3 barrier poller

typedef unsigned int u32;
typedef unsigned short u16;
typedef unsigned int u32x4 __attribute__((ext_vector_type(4)));  // true 4-VGPR tuple

// bf16 copies (filled by convert kernels each call)
__device__ u16 g_w2b[H2dim * HIDdim];        // [4096][1000]
__device__ u16 g_w3t[H2dim * Mdim * Ndim];   // transposed: [4096][1024]

// ---- LDS layout (bytes) ----
#define OFF_WIH 0          // 12 x 5120 bf16 = 122880
#define OFF_WHH 122880     // 12 x 1000 bf16 = 24000
#define OFF_UNION 146880   // 10240: s_x bf16[5120] | s_pd f32[512]
#define OFF_H9 157120      // padded h: 125 chunks x 9 f32 = 4520
#define OFF_MISC 161640    // 216 floats
#define SMEM_BYTES 162560

#define MI_POST 0
#define MI_PRIOR 32
#define MI_INNOV 96
#define MI_KIN 128
#define MI_GI 192
#define MI_GH 204

__device__ __forceinline__ u16 f2bf(float f) {
  u32 u = __float_as_uint(f);
  return (u16)((u + 0x7fffu + ((u >> 16) & 1u)) >> 16);
}
__device__ __forceinline__ float bflo(u32 u) { return __uint_as_float(u << 16); }
__device__ __forceinline__ float bfhi(u32 u) { return __uint_as_float(u & 0xffff0000u); }

__device__ __forceinline__ float dot4(float4 a, float4 b) {
  return a.x * b.x + a.y * b.y + a.z * b.z + a.w * b.w;
}
__device__ __forceinline__ float dot8_bb(uint4 a, uint4 b) {
  float s = 0.f;
  s = fmaf(bflo(a.x), bflo(b.x), s); s = fmaf(bfhi(a.x), bfhi(b.x), s);
  s = fmaf(bflo(a.y), bflo(b.y), s); s = fmaf(bfhi(a.y), bfhi(b.y), s);
  s = fmaf(bflo(a.z), bflo(b.z), s); s = fmaf(bfhi(a.z), bfhi(b.z), s);
  s = fmaf(bflo(a.w), bflo(b.w), s); s = fmaf(bfhi(a.w), bfhi(b.w), s);
  return s;
}
__device__ __forceinline__ float dot8_bf(uint4 a, const float* x8) {
  float s = 0.f;
  s = fmaf(bflo(a.x), x8[0], s); s = fmaf(bfhi(a.x), x8[1], s);
  s = fmaf(bflo(a.y), x8[2], s); s = fmaf(bfhi(a.y), x8[3], s);
  s = fmaf(bflo(a.z), x8[4], s); s = fmaf(bfhi(a.z), x8[5], s);
  s = fmaf(bflo(a.w), x8[6], s); s = fmaf(bfhi(a.w), x8[7], s);
  return s;
}

__device__ __forceinline__ float wave_reduce64(float v) {
#pragma unroll
  for (int off = 32; off >= 1; off >>= 1) v += __shfl_xor(v, off, 64);
  return v;
}

// ---- uncached (coherence-point) access helpers ----
__device__ __forceinline__ uint4 ldg_cg4u(const void* p) {
  uint4 r;
  asm volatile("global_load_dwordx4 %0, %1, off sc0 sc1\n\ts_waitcnt vmcnt(0)"
               : "=v"(r) : "v"(p) : "memory");
  return r;
}
__device__ __forceinline__ void stg_cg4u(void* p, u32 a, u32 b, u32 c, u32 d) {
  u32x4 v; v.x = a; v.y = b; v.z = c; v.w = d;   // ext_vector: valid "v" input
  asm volatile("global_store_dwordx4 %0, %1, off sc0 sc1" :: "v"(p), "v"(v) : "memory");
}
// 16 coherent dword loads at 128B stride, batch-issued, ONE vmcnt round trip.
// Deterministic sum order g=0..15.
__device__ __forceinline__ float ldg_sum16_cg(const float* p) {
  float r0, r1, r2, r3, r4, r5, r6, r7, r8, r9, r10, r11, r12, r13, r14, r15;
  asm volatile(
      "global_load_dword %0, %16, off sc0 sc1\n\t"
      "global_load_dword %1, %16, off offset:128 sc0 sc1\n\t"
      "global_load_dword %2, %16, off offset:256 sc0 sc1\n\t"
      "global_load_dword %3, %16, off offset:384 sc0 sc1\n\t"
      "global_load_dword %4, %16, off offset:512 sc0 sc1\n\t"
      "global_load_dword %5, %16, off offset:640 sc0 sc1\n\t"
      "global_load_dword %6, %16, off offset:768 sc0 sc1\n\t"
      "global_load_dword %7, %16, off offset:896 sc0 sc1\n\t"
      "global_load_dword %8, %16, off offset:1024 sc0 sc1\n\t"
      "global_load_dword %9, %16, off offset:1152 sc0 sc1\n\t"
      "global_load_dword %10, %16, off offset:1280 sc0 sc1\n\t"
      "global_load_dword %11, %16, off offset:1408 sc0 sc1\n\t"
      "global_load_dword %12, %16, off offset:1536 sc0 sc1\n\t"
      "global_load_dword %13, %16, off offset:1664 sc0 sc1\n\t"
      "global_load_dword %14, %16, off offset:1792 sc0 sc1\n\t"
      "global_load_dword %15, %16, off offset:1920 sc0 sc1\n\t"
      "s_waitcnt vmcnt(0)"
      : "=&v"(r0), "=&v"(r1), "=&v"(r2), "=&v"(r3), "=&v"(r4), "=&v"(r5),
        "=&v"(r6), "=&v"(r7), "=&v"(r8), "=&v"(r9), "=&v"(r10), "=&v"(r11),
        "=&v"(r12), "=&v"(r13), "=&v"(r14), "=&v"(r15)
      : "v"(p) : "memory");
  return (((r0 + r1) + (r2 + r3)) + ((r4 + r5) + (r6 + r7))) +
         (((r8 + r9) + (r10 + r11)) + ((r12 + r13) + (r14 + r15)));
}

// ---- two-level grid barrier (R5-proven): 16 group counters (<=16 writers each)
// -> level-2 counter -> go line (ONE write per barrier; pollers read only).
__device__ __forceinline__ void gb_arrive(u32* bar) {
  asm volatile("s_waitcnt vmcnt(0)" ::: "memory");
  __syncthreads();
  if (threadIdx.x == POLLER) {
    u32 g = (u32)blockIdx.x & 15u;
    u32 a = __hip_atomic_fetch_add(bar + g * 16, 1u, __ATOMIC_RELAXED,
                                   __HIP_MEMORY_SCOPE_AGENT);
    if ((a & 15u) == 15u) {
      u32 b = __hip_atomic_fetch_add(bar + 256, 1u, __ATOMIC_RELAXED,
                                     __HIP_MEMORY_SCOPE_AGENT);
      if ((b & 15u) == 15u)
        __hip_atomic_fetch_add(bar + 320, 1u, __ATOMIC_RELAXED,
                               __HIP_MEMORY_SCOPE_AGENT);
    }
  }
}
__device__ __forceinline__ void gb_wait(u32* bar, u32 nb) {
  if (threadIdx.x == POLLER) {
    while (__hip_atomic_load(bar + 320, __ATOMIC_RELAXED,
                             __HIP_MEMORY_SCOPE_AGENT) < nb)
      __builtin_amdgcn_s_sleep(1);
  }
  __syncthreads();
}

__global__ void convert_w2(const float* __restrict__ W2) {
  int i = blockIdx.x * 1024 + threadIdx.x;
  if (i < H2dim * HIDdim) g_w2b[i] = f2bf(W2[i]);
}

__global__ void convert_w3t(const float* __restrict__ W3) {
  __shared__ float tile[32][33];
  int tr = blockIdx.x >> 7;    // 0..31
  int tc = blockIdx.x & 127;   // 0..127
  int r0 = tr * 32, c0 = tc * 32;
  int j = threadIdx.x & 31, i0 = threadIdx.x >> 5;
#pragma unroll
  for (int p = 0; p < 4; ++p) {
    int i = i0 + p * 8;
    tile[i][j] = W3[(size_t)(r0 + i) * H2dim + c0 + j];
  }
  __syncthreads();
#pragma unroll
  for (int p = 0; p < 4; ++p) {
    int i = i0 + p * 8;
    g_w3t[(size_t)(c0 + i) * 1024 + r0 + j] = f2bf(tile[j][i]);
  }
}

// Delta reduction: TWO-LEVEL atomics (R8's 256-writers-per-line regressed;
// the <=16-writers law applies to atomic lines too). 16 group buffers of 32
// floats (one 128B line each), parity double-buffered. C_t: WG atomics into
// line wg&15 (16 writers/line). A_t: wave-0 lane reads 16 dwords at 128B
// stride in one batched round trip. wg0 zeroes the consumed buffer after its
// x-poll (x complete => all WGs finished A_t reads); the zero drains at wg0's
// S3 arrive, ordering it before any C_{t+2} atomic.
// x/h exchanges: tagged single-transaction stores (R7-proven).
__global__ void __launch_bounds__(NTHR)
knet_kernel(const float* __restrict__ y, const float* __restrict__ F,
            const float* __restrict__ Hm, const float* __restrict__ m1x0,
            const float* __restrict__ h0, const float* __restrict__ W1,
            const float* __restrict__ b1, const float* __restrict__ Wih,
            const float* __restrict__ bih, const float* __restrict__ Whh,
            const float* __restrict__ bhh, const float* __restrict__ b2,
            const float* __restrict__ b3, float* __restrict__ out,
            u32* bar, u32* xbt, u32* hbt, float* acc) {
  extern __shared__ char smem[];
  u16* s_wih = (u16*)(smem + OFF_WIH);
  u16* s_whh = (u16*)(smem + OFF_WHH);
  u16* s_x = (u16*)(smem + OFF_UNION);
  float* s_pd = (float*)(smem + OFF_UNION);
  float* s_h9 = (float*)(smem + OFF_H9);
  float* s_m = (float*)(smem + OFF_MISC);
  float* s_post = s_m + MI_POST;
  float* s_prior = s_m + MI_PRIOR;
  float* s_innov = s_m + MI_INNOV;
  float* s_kin = s_m + MI_KIN;
  float* s_gi = s_m + MI_GI;
  float* s_gh = s_m + MI_GH;

  const int tid = threadIdx.x;
  const int w = tid >> 6;
  const int lane = tid & 63;
  const int wg = blockIdx.x;
  const int k0 = wg * 4;
  const bool gru_wg = (wg < 250);
  u32 nb = 0;

  // ---------------- prologue: LDS weight staging ----------------
  if (gru_wg) {
#pragma unroll 1
    for (int r = 0; r < 12; ++r) {
      const float* src = Wih + (size_t)((r >> 2) * HIDdim + k0 + (r & 3)) * H1dim;
      u16* dst = s_wih + r * H1dim;
      for (int e = tid; e < H1dim; e += NTHR) dst[e] = f2bf(src[e]);
    }
#pragma unroll 1
    for (int r = 0; r < 12; ++r) {
      const float* src = Whh + (size_t)((r >> 2) * HIDdim + k0 + (r & 3)) * HIDdim;
      u16* dst = s_whh + r * HIDdim;
      for (int e = tid; e < HIDdim; e += NTHR) dst[e] = f2bf(src[e]);
    }
  }
  if (tid < 250) {
    float4 hv = ((const float4*)h0)[tid];
    int b0 = tid * 4;
    s_h9[((b0 + 0) >> 3) * 9 + ((b0 + 0) & 7)] = hv.x;
    s_h9[((b0 + 1) >> 3) * 9 + ((b0 + 1) & 7)] = hv.y;
    s_h9[((b0 + 2) >> 3) * 9 + ((b0 + 2) & 7)] = hv.z;
    s_h9[((b0 + 3) >> 3) * 9 + ((b0 + 3) & 7)] = hv.w;
  }
  __syncthreads();

  const int c2 = wg * 16 + w;            // this wave's W2/W3t row
  // wave-0 persistent state: prior (lanes<32), prefetched y row, b3·innov term
  float prior = 0.f, bb = 0.f, yv = 0.f;
  if (w == 0 && lane < 32) {
    prior = m1x0[lane];
    yv = y[lane];  // y row 0
  }

  // gh: Whh @ h (needs staged s_whh/s_h9)
  auto gh_compute = [&]() {
    int base = (w - 12) * 3;
#pragma unroll
    for (int rr = 0; rr < 3; ++rr) {
      int r = base + rr;
      const uint4* wr = (const uint4*)(s_whh + r * HIDdim);
      float acc_ = dot8_bf(wr[lane], s_h9 + lane * 9);
      if (lane < 61) acc_ += dot8_bf(wr[lane + 64], s_h9 + (lane + 64) * 9);
      acc_ = wave_reduce64(acc_);
      if (lane == 0) s_gh[r] = acc_ + bhh[(r >> 2) * HIDdim + k0 + (r & 3)];
    }
  };
  if (gru_wg && w >= 12) gh_compute();

  for (int t = 0; t < Tsteps; ++t) {
    const u32 want = (u32)(t + 1);
    const int parR = (t + 1) & 1;   // buffer consumed this step ((t-1)&1)
    const int parW = t & 1;         // buffer C_t accumulates into
    // ---------------- Phase A: serial chain (wave 0 only) ----------------
    if (w == 0) {
      float p = 0.f, inn = 0.f;
      float prev = prior;
      if (lane < 32) {
        if (t == 0) {
          p = m1x0[lane];
        } else {
          float d = ldg_sum16_cg(acc + parR * 512 + lane);  // 16-group delta
          p = prior + d + bb;  // bb = b3·innov from last S3 shadow
          if (wg == 0) out[(t - 1) * Mdim + lane] = p;
        }
        s_post[lane] = p;
      }
      asm volatile("" ::: "memory");
      if (lane < 32) {  // prior = F @ post
        const float4* Fr = (const float4*)(F + lane * Mdim);
        const float4* pp = (const float4*)s_post;
        float s = 0.f;
#pragma unroll
        for (int j = 0; j < 8; ++j) s += dot4(Fr[j], pp[j]);
        prior = s;
        s_prior[lane] = s;
      }
      asm volatile("" ::: "memory");
      if (lane < 32) {  // innov = y_t - H @ prior
        const float4* Hr = (const float4*)(Hm + lane * Mdim);
        const float4* pp = (const float4*)s_prior;
        float s = 0.f;
#pragma unroll
        for (int j = 0; j < 8; ++j) s += dot4(Hr[j], pp[j]);
        inn = yv - s;
        s_innov[lane] = inn;
      }
      // kin: lanes<32 innov, lanes>=32 (post - prev_prior); normalize halves
      float vd = __shfl(p, lane & 31, 64) - __shfl(prev, lane & 31, 64);
      float v = (lane < 32) ? inn : vd;
      float sq = v * v;
#pragma unroll
      for (int off = 16; off >= 1; off >>= 1) sq += __shfl_xor(sq, off, 32);
      s_kin[lane] = v / fmaxf(sqrtf(sq), 1e-12f);
    }
    __syncthreads();   // publish s_innov/s_kin

    // ---- wave 0: W1 rows (3 lanes/row) -> pack -> tagged x store ----
    if (w == 0) {
      int r = lane / 3;
      int p = lane - r * 3;
      float acc_ = 0.f;
      if (r < 20) {
        const float4* Wr = (const float4*)W1 + (size_t)(wg * 20 + r) * 16;
        const float4* kc = (const float4*)s_kin;
#pragma unroll
        for (int c = p; c < 16; c += 3) acc_ += dot4(Wr[c], kc[c]);
      }
      int rr = (r < 20) ? r : 0;
      float a1v = __shfl(acc_, rr * 3 + 1, 64);
      float a2v = __shfl(acc_, rr * 3 + 2, 64);
      u32 myval = 0;
      if (r < 20 && p == 0)
        myval = (u32)f2bf(fmaxf(acc_ + a1v + a2v + b1[wg * 20 + r], 0.f));
      u32 vs[7];
      int q = (lane < 3) ? lane : 0;
#pragma unroll
      for (int s2 = 0; s2 < 7; ++s2) {
        int ridx = q * 7 + s2;
        vs[s2] = __shfl(myval, (ridx < 20 ? ridx : 0) * 3, 64);
      }
      if (lane < 3) {
        stg_cg4u((char*)xbt + (size_t)(wg * 3 + lane) * 16,
                 vs[0] | (vs[1] << 16),
                 vs[2] | (vs[3] << 16),
                 vs[4] | (vs[5] << 16),
                 ((lane == 2) ? 0u : vs[6]) | (want << 16));
      }
    }
    // ---- all waves: u = W3t row · innov, W2 row prefetch (h-independent;
    //      iteration-local register lifetimes — NOT loop-carried) ----
    float u;
    uint4 w2a, w2b_;
    {
      const uint4* tr3 = (const uint4*)(g_w3t + (size_t)c2 * 1024);
      uint4 t0 = tr3[2 * lane], t1 = tr3[2 * lane + 1];
      const float* iv = s_innov + 16 * (lane & 1);
      u = dot8_bf(t0, iv) + dot8_bf(t1, iv + 8);
      u += __shfl_xor(u, 1, 64);
      const uint4* w2p = (const uint4*)(g_w2b + (size_t)c2 * HIDdim);
      w2a = w2p[lane];
      w2b_ = (lane < 61) ? w2p[lane + 64] : make_uint4(0u, 0u, 0u, 0u);
    }
    // ---- x poll+stage: gru WGs, waves 4-15 own one group each ----
    if (gru_wg && tid >= 256) {
      int g = tid - 256;
      int swg = g / 3;
      int q = g - swg * 3;
      const char* gp = (const char*)xbt + (size_t)g * 16;
      uint4 v;
      for (;;) {
        v = ldg_cg4u(gp);
        if ((v.w >> 16) == want) break;
        __builtin_amdgcn_s_sleep(1);
      }
      u16* sx = (u16*)s_x;
      int base = swg * 20 + q * 7;
      sx[base + 0] = (u16)(v.x & 0xffff);
      sx[base + 1] = (u16)(v.x >> 16);
      sx[base + 2] = (u16)(v.y & 0xffff);
      sx[base + 3] = (u16)(v.y >> 16);
      sx[base + 4] = (u16)(v.z & 0xffff);
      sx[base + 5] = (u16)(v.z >> 16);
      if (q != 2) sx[base + 6] = (u16)(v.w & 0xffff);
    }
    __syncthreads();   // s_x ready (=> all 256 WGs published x => all A_t done)

    // ---- wg0: re-zero the consumed 16-group buffer (safe point, see header) ----
    if (wg == 0 && tid < 128)
      stg_cg4u(acc + parR * 512 + tid * 4, 0u, 0u, 0u, 0u);

    // ---------------- gi: waves 0-11 ----------------
    if (gru_wg && w < 12) {
      const uint4* wr = (const uint4*)(s_wih + w * H1dim);
      const uint4* xr = (const uint4*)s_x;
      float acc_ = 0.f;
#pragma unroll
      for (int i = 0; i < 10; ++i) {
        int j = lane + 64 * i;
        acc_ += dot8_bb(wr[j], xr[j]);
      }
      acc_ = wave_reduce64(acc_);
      if (lane == 0) s_gi[w] = acc_ + bih[(w >> 2) * HIDdim + k0 + (w & 3)];
    }
    __syncthreads();   // s_gi ready

    // ---- gates -> tagged h store (wave 0 lanes 0-3; reads OLD s_h9 first) ----
    if (gru_wg && w == 0 && lane < 4) {
      int k = k0 + lane;
      float hold = s_h9[(k >> 3) * 9 + (k & 7)];
      float ir = s_gi[lane], iz = s_gi[4 + lane], ic = s_gi[8 + lane];
      float r = 1.f / (1.f + expf(-(ir + s_gh[lane])));
      float z = 1.f / (1.f + expf(-(iz + s_gh[4 + lane])));
      float c_ = tanhf(ic + r * s_gh[8 + lane]);
      float hv = (1.f - z) * c_ + z * hold;
      stg_cg4u((char*)hbt + (size_t)k * 16, __float_as_uint(hv), want, 0u, 0u);
    }
    // ---- h poll+stage: all WGs, one group per thread ----
    if (tid < HIDdim) {
      const char* gp = (const char*)hbt + (size_t)tid * 16;
      uint4 v;
      for (;;) {
        v = ldg_cg4u(gp);
        if (v.y == want) break;
        __builtin_amdgcn_s_sleep(1);
      }
      s_h9[(tid >> 3) * 9 + (tid & 7)] = __uint_as_float(v.x);
    }
    __syncthreads();   // s_h9 = h_t

    // ---------------- Phase C: l2 rows + two-level delta atomics ----------------
    {
      float acc_ = dot8_bf(w2a, s_h9 + lane * 9);
      if (lane < 61) acc_ += dot8_bf(w2b_, s_h9 + (lane + 64) * 9);
      acc_ = wave_reduce64(acc_);
      float l2c = fmaxf(acc_ + b2[c2], 0.f);
      if ((lane & 1) == 0) s_pd[w * 32 + (lane >> 1)] = l2c * u;
    }
    __syncthreads();
    if (tid < 32) {
      float pdv = 0.f;
#pragma unroll
      for (int ww = 0; ww < 16; ++ww) pdv += s_pd[ww * 32 + tid];
      __hip_atomic_fetch_add(acc + parW * 512 + (wg & 15) * 32 + tid, pdv,
                             __ATOMIC_RELAXED, __HIP_MEMORY_SCOPE_AGENT);
    }
    ++nb;
    gb_arrive(bar);              // S3: delta atomics drained (sole barrier)
    // S3 shadow: next step's gh (Whh@h_t), b3·innov_t, y[t+1] prefetch
    if (gru_wg && w >= 12) gh_compute();
    if (w == 0 && lane < 32) {
      int tn = (t + 1 < Tsteps) ? t + 1 : Tsteps - 1;
      yv = y[tn * Ndim + lane];
      float b = 0.f;
#pragma unroll 8
      for (int j = 0; j < 32; ++j) b = fmaf(b3[lane * 32 + j], s_innov[j], b);
      bb = b;
    }
    gb_wait(bar, nb);
  }

  // ---------------- epilogue: out row 511 ----------------
  if (wg == 0 && w == 0 && lane < 32) {
    float d = ldg_sum16_cg(acc + ((Tsteps - 1) & 1) * 512 + lane);
    out[(Tsteps - 1) * Mdim + lane] = prior + d + bb;  // bb from last S3 shadow
  }
}

extern "C" void kernel_launch(void* const* d_in, const int* in_sizes, int n_in,
                              void* d_out, int out_size, void* d_ws, size_t ws_size,
                              hipStream_t stream) {
  const float* y    = (const float*)d_in[0];
  const float* F    = (const float*)d_in[1];
  const float* Hm   = (const float*)d_in[2];
  const float* m1x0 = (const float*)d_in[3];
  const float* h0   = (const float*)d_in[4];
  const float* W1   = (const float*)d_in[5];
  const float* b1   = (const float*)d_in[6];
  const float* Wih  = (const float*)d_in[7];
  const float* bih  = (const float*)d_in[8];
  const float* Whh  = (const float*)d_in[9];
  const float* bhh  = (const float*)d_in[10];
  const float* W2   = (const float*)d_in[11];
  const float* b2   = (const float*)d_in[12];
  const float* W3   = (const float*)d_in[13];
  const float* b3   = (const float*)d_in[14];
  float* out = (float*)d_out;

  // ws layout: bar[0,4096); acc@4096 (2 parity x 512 f32 = 4KB);
  // xbt@8192 768x16B; hbt@20480 1000x16B. memset zeroes all control state.
  u32* bar   = (u32*)d_ws;
  float* acc = (float*)((char*)d_ws + 4096);
  u32* xbt   = (u32*)((char*)d_ws + 8192);
  u32* hbt   = (u32*)((char*)d_ws + 20480);

  convert_w2<<<4000, 1024, 0, stream>>>(W2);
  convert_w3t<<<4096, 256, 0, stream>>>(W3);
  hipMemsetAsync(d_ws, 0, 36864, stream);
  hipFuncSetAttribute((const void*)knet_kernel,
                      hipFuncAttributeMaxDynamicSharedMemorySize, SMEM_BYTES);
  void* args[] = {&y, &F, &Hm, &m1x0, &h0, &W1, &b1, &Wih, &bih, &Whh, &bhh,
                  &b2, &b3, &out, &bar, &xbt, &hbt, &acc};
  hipLaunchCooperativeKernel((const void*)knet_kernel, dim3(NWG), dim3(NTHR),
                             args, SMEM_BYTES, stream);
}